// Round 6
// baseline (609.555 us; speedup 1.0000x reference)
//
#include <hip/hip_runtime.h>
#include <cmath>

// B=64, L=512, H=64, 2H=128, OUT=5
static constexpr int kB = 64, kL = 512, kH = 64, kH2 = 128, kOut = 5;

typedef short bf16x8 __attribute__((ext_vector_type(8)));
typedef float f32x4  __attribute__((ext_vector_type(4)));
typedef float f32x16 __attribute__((ext_vector_type(16)));

__device__ __forceinline__ unsigned short f2bf(float f) {
  unsigned u = __float_as_uint(f);
  unsigned r = (u + 0x7FFFu + ((u >> 16) & 1u)) >> 16;   // RNE
  return (unsigned short)r;
}

__device__ __forceinline__ void cvt8(const f32x4& v0, const f32x4& v1,
                                     bf16x8& hi, bf16x8& lo) {
  #pragma unroll
  for (int j = 0; j < 4; ++j) {
    unsigned short h0 = f2bf(v0[j]);
    unsigned short h1 = f2bf(v1[j]);
    hi[j]     = (short)h0;
    hi[j + 4] = (short)h1;
    lo[j]     = (short)f2bf(v0[j] - __uint_as_float(((unsigned)h0) << 16));
    lo[j + 4] = (short)f2bf(v1[j] - __uint_as_float(((unsigned)h1) << 16));
  }
}

// ---- prepass: V fp32 -> bf16 row-major [i][p][q]; W -> Wt bf16 [i][p] ----
__global__ void prep_k(const float* __restrict__ V, const float* __restrict__ W,
                       unsigned short* __restrict__ vhi, unsigned short* __restrict__ wt) {
  int idx = blockIdx.x * 256 + threadIdx.x;
  if (idx < kH * kH2 * kH2) {
    vhi[idx] = f2bf(V[idx]);
  } else {
    int widx = idx - kH * kH2 * kH2;
    if (widx < kH * kH2) {
      int i = widx >> 7, p = widx & 127;
      wt[widx] = f2bf(W[p * kH + i]);      // Wt[i][p] = W[p][i]
    }
  }
}

// ---- node-stationary combine (R6): 32x32 MFMA engine + res-LDS write staging
// Per block: 128 nodes, IS i's (IS<=16). C (hi/lo bf16 + fp32) in registers for
// the whole i-loop; V_i staged to 32KB LDS per ic (XOR-16 swizzle, conflict-free);
//   D[p,m] = sum_q V_i[p,q] C[m,q]   (32x32x16 MFMA, 2 indep hi/lo chains)
//   r[m,i] = sum_p C[m,p] D[p,m]     (fp32 dot over C/D regs + shfl_xor 32)
// Results accumulate in res[128][17] LDS; epilogue writes contiguous IS-float
// row-slices (full 64B lines at IS=16) -> no partial-line churn (R5's killer).
// 3 blocks/CU: other blocks' MFMA covers this block's stage+barrier phase.
template<bool FIRST>
__global__ __launch_bounds__(256, 3) void combine6_k(
    const float* __restrict__ in, const int* __restrict__ tokens,
    const float* __restrict__ embed, const unsigned short* __restrict__ vhi,
    const unsigned short* __restrict__ wt, const float* __restrict__ bias,
    float* __restrict__ out, int M, int IS)
{
  __shared__ unsigned short Vs[kH2 * kH2];      // 32 KB, swizzled 16B chunks
  __shared__ float res[128 * 17];               // (m, i) staging; 17 kills conflicts

  const int t    = threadIdx.x;
  const int lane = t & 63, w = t >> 6;
  const int hl   = lane >> 5;                   // K-half / row-half selector
  const int r31  = lane & 31;
  const int m0   = (int)blockIdx.x * 128;
  const int i0   = (int)blockIdx.y * IS;
  const int Mrows = (M < 128) ? M : 128;
  const bool has_rows = (w * 32) < Mrows;

  auto stageV = [&](int i) {
    const unsigned short* vsrc = vhi + (size_t)i * (kH2 * kH2);
    #pragma unroll
    for (int k = 0; k < 8; ++k) {
      int chunk = t + k * 256;                  // physical 16B chunk 0..2047
      int p   = chunk >> 4;
      int c16 = (chunk & 15) ^ (p & 15);        // logical k-chunk (swizzle)
      const unsigned short* g = vsrc + p * kH2 + c16 * 8;
      __builtin_amdgcn_global_load_lds(
          (const __attribute__((address_space(1))) unsigned int*)g,
          (__attribute__((address_space(3))) unsigned int*)
              ((char*)&Vs[0] + (size_t)chunk * 16),
          16, 0, 0);
    }
  };

  stageV(i0);                                   // in flight during setup

  bf16x8 bh[8], bl[8];                          // C hi/lo, K=128 in 8 slices
  f32x4  Cred[4][4];                            // C fp32 in C/D-row layout
  float  wxr[8];                                // Wx+bias for rows 0..15 (hl pair)

  if (has_rows) {
    const int m = m0 + w * 32 + r31;
    const float* crow = nullptr;
    int tokA = 0, tokB = 0;
    if (FIRST) {
      int b = m >> 8, j = m & 255;              // Nout=256 at level 1
      tokA = tokens[b * kL + 2 * j];
      tokB = tokens[b * kL + 2 * j + 1];
    } else {
      crow = in + (size_t)m * kH2;
    }
    #pragma unroll
    for (int ks = 0; ks < 8; ++ks) {            // k = ks*16 + hl*8 ..+8
      int q0 = ks * 16 + hl * 8;
      const float* src = FIRST
          ? (embed + (size_t)(q0 < 64 ? tokA : tokB) * kH + (q0 & 63))
          : (crow + q0);
      f32x4 v0 = *(const f32x4*)src;
      f32x4 v1 = *(const f32x4*)(src + 4);
      cvt8(v0, v1, bh[ks], bl[ks]);
    }
    #pragma unroll
    for (int pt = 0; pt < 4; ++pt)
      #pragma unroll
      for (int j = 0; j < 4; ++j) {             // p = pt*32 + j*8 + hl*4 ..+4
        int p0 = pt * 32 + j * 8 + hl * 4;
        const float* src = FIRST
            ? (embed + (size_t)(p0 < 64 ? tokA : tokB) * kH + (p0 & 63))
            : (crow + p0);
        Cred[pt][j] = *(const f32x4*)src;
      }
    // Wx: D'[i,m] = sum_p Wt[i,p] C[m,p]; C/D rows 0..15 cover IS<=16
    {
      int irow = i0 + r31; if (irow > kH - 1) irow = kH - 1;
      f32x16 acc = {};
      #pragma unroll
      for (int ks = 0; ks < 8; ++ks) {
        bf16x8 a = *(const bf16x8*)(wt + (size_t)irow * kH2 + ks * 16 + hl * 8);
        acc = __builtin_amdgcn_mfma_f32_32x32x16_bf16(a, bh[ks], acc, 0, 0, 0);
      }
      #pragma unroll
      for (int reg = 0; reg < 8; ++reg) {
        int ii = (reg & 3) + 8 * (reg >> 2) + 4 * hl;   // 0..15
        int ib = i0 + ii; if (ib > kH - 1) ib = kH - 1;
        wxr[reg] = acc[reg] + bias[ib];
      }
    }
  }

  __syncthreads();                              // Vs[i0] resident

  for (int ic = 0; ic < IS; ++ic) {
    if (has_rows) {
      float gsum = 0.f;
      #pragma unroll
      for (int pt = 0; pt < 4; ++pt) {
        const int p  = pt * 32 + r31;           // A-frag row = V row p
        const int pm = p & 15;
        const char* vrow = (const char*)&Vs[0] + (size_t)p * 256;
        f32x16 ah = {}, al = {};                // 2 independent chains
        #pragma unroll
        for (int ks = 0; ks < 8; ++ks) {
          int cc = (ks * 2 + hl) ^ pm;          // swizzled chunk
          bf16x8 vf = *(const bf16x8*)(vrow + cc * 16);
          ah = __builtin_amdgcn_mfma_f32_32x32x16_bf16(vf, bh[ks], ah, 0, 0, 0);
          al = __builtin_amdgcn_mfma_f32_32x32x16_bf16(vf, bl[ks], al, 0, 0, 0);
        }
        #pragma unroll
        for (int reg = 0; reg < 16; ++reg)      // p' = pt*32+(reg&3)+8*(reg>>2)+4*hl
          gsum = fmaf(Cred[pt][reg >> 2][reg & 3], ah[reg] + al[reg], gsum);
      }
      gsum += __shfl_xor(gsum, 32);             // join p-halves
      if (hl == ((ic >> 2) & 1)) {              // lane half holding wx for i=ic
        int reg = (ic & 3) + 4 * (ic >> 3);
        res[(w * 32 + r31) * 17 + ic] = tanhf(gsum + wxr[reg]);
      }
    }
    __syncthreads();                            // all reads of Vs done
    if (ic + 1 < IS) {
      stageV(i0 + ic + 1);
      __syncthreads();                          // Vs[ic+1] resident
    }
  }

  // epilogue: contiguous IS-float row-slices (full cache lines at IS=16)
  for (int idx = t; idx < Mrows * IS; idx += 256) {
    int m = idx / IS, ii = idx - m * IS;
    out[(size_t)(m0 + m) * kH + i0 + ii] = res[m * 17 + ii];
  }
}

// ---- head: logits = root @ Wout + bout; log_softmax ----
__global__ void head_k(const float* __restrict__ root,
                       const float* __restrict__ Wout,
                       const float* __restrict__ bout,
                       float* __restrict__ out) {
  int b = threadIdx.x;
  float l[kOut];
  #pragma unroll
  for (int o = 0; o < kOut; ++o) l[o] = bout[o];
  for (int h = 0; h < kH; ++h) {
    float r = root[b * kH + h];
    #pragma unroll
    for (int o = 0; o < kOut; ++o) l[o] = fmaf(r, Wout[h * kOut + o], l[o]);
  }
  float mx = l[0];
  #pragma unroll
  for (int o = 1; o < kOut; ++o) mx = fmaxf(mx, l[o]);
  float s = 0.f;
  #pragma unroll
  for (int o = 0; o < kOut; ++o) s += expf(l[o] - mx);
  float lse = logf(s);
  #pragma unroll
  for (int o = 0; o < kOut; ++o) out[b * kOut + o] = l[o] - mx - lse;
}

extern "C" void kernel_launch(void* const* d_in, const int* in_sizes, int n_in,
                              void* d_out, int out_size, void* d_ws, size_t ws_size,
                              hipStream_t stream) {
  const int*   tokens = (const int*)  d_in[0];
  const float* embed  = (const float*)d_in[1];
  const float* V      = (const float*)d_in[2];
  const float* W      = (const float*)d_in[3];
  const float* bias   = (const float*)d_in[4];
  const float* Wout   = (const float*)d_in[5];
  const float* bout   = (const float*)d_in[6];
  float* out = (float*)d_out;

  // ws: vhi 2MB | wt 16KB | bufA 4MB | bufB 2MB
  char* ws = (char*)d_ws;
  unsigned short* vhi = (unsigned short*)ws;
  unsigned short* wt  = (unsigned short*)(ws + 2097152);
  float* bufA = (float*)(ws + 2097152 + 16384);
  float* bufB = (float*)(ws + 2097152 + 16384 + 4194304);

  int nprep = kH * kH2 * kH2 + kH * kH2;
  prep_k<<<dim3((nprep + 255) / 256), 256, 0, stream>>>(V, W, vhi, wt);

  const float* cur = nullptr;
  float* nxt = bufA;
  bool first = true;
  for (int Nout = 256; Nout >= 1; Nout >>= 1) {
    int M  = kB * Nout;
    int gx = (M >= 128) ? (M / 128) : 1;
    int IS = gx / 8; if (IS < 1) IS = 1; if (IS > 16) IS = 16;
    dim3 grid(gx, 64 / IS);                     // L1: (128,4)=512 blocks, IS=16
    if (first)
      combine6_k<true ><<<grid, 256, 0, stream>>>(nullptr, tokens, embed, vhi, wt, bias, nxt, M, IS);
    else
      combine6_k<false><<<grid, 256, 0, stream>>>(cur, nullptr, nullptr, vhi, wt, bias, nxt, M, IS);
    first = false;
    cur = nxt;
    nxt = (nxt == bufA) ? bufB : bufA;
  }
  head_k<<<1, 64, 0, stream>>>(cur, Wout, bout, out);   // cur == bufA after 9 levels
}

// Round 7
// 317.068 us; speedup vs baseline: 1.9225x; 1.9225x over previous
//
#include <hip/hip_runtime.h>
#include <cmath>

// B=64, L=512, H=64, 2H=128, OUT=5
static constexpr int kB = 64, kL = 512, kH = 64, kH2 = 128, kOut = 5;

typedef short bf16x8 __attribute__((ext_vector_type(8)));
typedef float f32x4  __attribute__((ext_vector_type(4)));
typedef float f32x16 __attribute__((ext_vector_type(16)));

__device__ __forceinline__ unsigned short f2bf(float f) {
  unsigned u = __float_as_uint(f);
  unsigned r = (u + 0x7FFFu + ((u >> 16) & 1u)) >> 16;   // RNE
  return (unsigned short)r;
}

__device__ __forceinline__ bf16x8 cvt8hi(const f32x4& v0, const f32x4& v1) {
  bf16x8 hi;
  #pragma unroll
  for (int j = 0; j < 4; ++j) {
    hi[j]     = (short)f2bf(v0[j]);
    hi[j + 4] = (short)f2bf(v1[j]);
  }
  return hi;
}

// ---- prepass: V fp32 -> bf16 row-major [i][p][q]; W -> Wt bf16 [i][p] ----
__global__ void prep_k(const float* __restrict__ V, const float* __restrict__ W,
                       unsigned short* __restrict__ vhi, unsigned short* __restrict__ wt) {
  int idx = blockIdx.x * 256 + threadIdx.x;
  if (idx < kH * kH2 * kH2) {
    vhi[idx] = f2bf(V[idx]);
  } else {
    int widx = idx - kH * kH2 * kH2;
    if (widx < kH * kH2) {
      int i = widx >> 7, p = widx & 127;
      wt[widx] = f2bf(W[p * kH + i]);      // Wt[i][p] = W[p][i]
    }
  }
}

// ---- node-stationary combine (R7): single-bf16 C so everything FITS in VGPRs
// Register budget (the R5/R6 lesson: ~220 declared -> compiler spilled to
// scratch + rematerialized from global = FETCH/WRITE explosion):
//   bh[8] 32 + Cred[4][4] 64 + f32x16 acc 16 + wxr 8 + misc ~20 = ~140 <= 168 cap.
// Per ic: D[p,m] = sum_q V_i[p,q] C[m,q]  (32x32x16 MFMA, A=V from LDS, XOR-16
// swizzle, conflict-free); r[m,i] = sum_p C[m,p] D[p,m] (fp32 dot + shfl_xor 32).
// Wx+bias once per block into wxr via one 32x32 MFMA tile. Results staged in
// res[128][17] LDS; epilogue writes contiguous IS-float row-slices (full lines
// at IS=16 -> no partial-line churn).
template<bool FIRST>
__global__ __launch_bounds__(256, 3) void combine7_k(
    const float* __restrict__ in, const int* __restrict__ tokens,
    const float* __restrict__ embed, const unsigned short* __restrict__ vhi,
    const unsigned short* __restrict__ wt, const float* __restrict__ bias,
    float* __restrict__ out, int M, int IS)
{
  __shared__ unsigned short Vs[kH2 * kH2];      // 32 KB, swizzled 16B chunks
  __shared__ float res[128 * 17];               // (m,i) staging; 17 kills conflicts

  const int t    = threadIdx.x;
  const int lane = t & 63, w = t >> 6;
  const int hl   = lane >> 5;                   // K-half / row-half selector
  const int r31  = lane & 31;
  const int m0   = (int)blockIdx.x * 128;
  const int i0   = (int)blockIdx.y * IS;
  const int Mrows = (M < 128) ? M : 128;
  const bool has_rows = (w * 32) < Mrows;

  auto stageV = [&](int i) {
    const unsigned short* vsrc = vhi + (size_t)i * (kH2 * kH2);
    #pragma unroll
    for (int k = 0; k < 8; ++k) {
      int chunk = t + k * 256;                  // physical 16B chunk 0..2047
      int p   = chunk >> 4;
      int c16 = (chunk & 15) ^ (p & 15);        // logical k-chunk (swizzle)
      const unsigned short* g = vsrc + p * kH2 + c16 * 8;
      __builtin_amdgcn_global_load_lds(
          (const __attribute__((address_space(1))) unsigned int*)g,
          (__attribute__((address_space(3))) unsigned int*)
              ((char*)&Vs[0] + (size_t)chunk * 16),
          16, 0, 0);
    }
  };

  stageV(i0);                                   // in flight during setup

  bf16x8 bh[8];                                 // C bf16 (hi only), 8 K-slices
  f32x4  Cred[4][4];                            // C fp32 in C/D-row layout
  float  wxr[8];                                // Wx+bias for rows 0..15 (hl pair)

  if (has_rows) {
    const int m = m0 + w * 32 + r31;
    const float* crow = nullptr;
    int tokA = 0, tokB = 0;
    if (FIRST) {
      int b = m >> 8, j = m & 255;              // Nout=256 at level 1
      tokA = tokens[b * kL + 2 * j];
      tokB = tokens[b * kL + 2 * j + 1];
    } else {
      crow = in + (size_t)m * kH2;
    }
    #pragma unroll
    for (int ks = 0; ks < 8; ++ks) {            // k = ks*16 + hl*8 ..+8
      int q0 = ks * 16 + hl * 8;
      const float* src = FIRST
          ? (embed + (size_t)(q0 < 64 ? tokA : tokB) * kH + (q0 & 63))
          : (crow + q0);
      f32x4 v0 = *(const f32x4*)src;
      f32x4 v1 = *(const f32x4*)(src + 4);
      bh[ks] = cvt8hi(v0, v1);
    }
    #pragma unroll
    for (int pt = 0; pt < 4; ++pt)
      #pragma unroll
      for (int j = 0; j < 4; ++j) {             // p = pt*32 + j*8 + hl*4 ..+4
        int p0 = pt * 32 + j * 8 + hl * 4;
        const float* src = FIRST
            ? (embed + (size_t)(p0 < 64 ? tokA : tokB) * kH + (p0 & 63))
            : (crow + p0);
        Cred[pt][j] = *(const f32x4*)src;
      }
    // Wx: D'[i,m] = sum_p Wt[i,p] C[m,p]; C/D rows 0..15 cover IS<=16
    {
      int irow = i0 + r31; if (irow > kH - 1) irow = kH - 1;
      f32x16 acc = {};
      #pragma unroll
      for (int ks = 0; ks < 8; ++ks) {
        bf16x8 a = *(const bf16x8*)(wt + (size_t)irow * kH2 + ks * 16 + hl * 8);
        acc = __builtin_amdgcn_mfma_f32_32x32x16_bf16(a, bh[ks], acc, 0, 0, 0);
      }
      #pragma unroll
      for (int reg = 0; reg < 8; ++reg) {
        int ii = (reg & 3) + 8 * (reg >> 2) + 4 * hl;   // 0..15
        int ib = i0 + ii; if (ib > kH - 1) ib = kH - 1;
        wxr[reg] = acc[reg] + bias[ib];
      }
    }
  }

  __syncthreads();                              // Vs[i0] resident

  for (int ic = 0; ic < IS; ++ic) {
    if (has_rows) {
      float gsum = 0.f;
      #pragma unroll
      for (int pt = 0; pt < 4; ++pt) {
        const int p  = pt * 32 + r31;           // A-frag row = V row p
        const int pm = p & 15;
        const char* vrow = (const char*)&Vs[0] + (size_t)p * 256;
        f32x16 ah = {};
        #pragma unroll
        for (int ks = 0; ks < 8; ++ks) {
          int cc = (ks * 2 + hl) ^ pm;          // swizzled chunk
          bf16x8 vf = *(const bf16x8*)(vrow + cc * 16);
          ah = __builtin_amdgcn_mfma_f32_32x32x16_bf16(vf, bh[ks], ah, 0, 0, 0);
        }
        #pragma unroll
        for (int reg = 0; reg < 16; ++reg)      // p' = pt*32+(reg&3)+8*(reg>>2)+4*hl
          gsum = fmaf(Cred[pt][reg >> 2][reg & 3], ah[reg], gsum);
      }
      gsum += __shfl_xor(gsum, 32);             // join p-halves
      if (hl == ((ic >> 2) & 1)) {              // lane half holding wx for i=ic
        int reg = (ic & 3) + 4 * (ic >> 3);
        res[(w * 32 + r31) * 17 + ic] = tanhf(gsum + wxr[reg]);
      }
    }
    __syncthreads();                            // all reads of Vs done
    if (ic + 1 < IS) {
      stageV(i0 + ic + 1);
      __syncthreads();                          // Vs[ic+1] resident
    }
  }

  // epilogue: contiguous IS-float row-slices (full cache lines at IS=16)
  const int sh = 31 - __clz(IS);                // IS is a power of 2
  for (int idx = t; idx < Mrows * IS; idx += 256) {
    int m = idx >> sh, ii = idx & (IS - 1);
    out[(size_t)(m0 + m) * kH + i0 + ii] = res[m * 17 + ii];
  }
}

// ---- head: logits = root @ Wout + bout; log_softmax ----
__global__ void head_k(const float* __restrict__ root,
                       const float* __restrict__ Wout,
                       const float* __restrict__ bout,
                       float* __restrict__ out) {
  int b = threadIdx.x;
  float l[kOut];
  #pragma unroll
  for (int o = 0; o < kOut; ++o) l[o] = bout[o];
  for (int h = 0; h < kH; ++h) {
    float r = root[b * kH + h];
    #pragma unroll
    for (int o = 0; o < kOut; ++o) l[o] = fmaf(r, Wout[h * kOut + o], l[o]);
  }
  float mx = l[0];
  #pragma unroll
  for (int o = 1; o < kOut; ++o) mx = fmaxf(mx, l[o]);
  float s = 0.f;
  #pragma unroll
  for (int o = 0; o < kOut; ++o) s += expf(l[o] - mx);
  float lse = logf(s);
  #pragma unroll
  for (int o = 0; o < kOut; ++o) out[b * kOut + o] = l[o] - mx - lse;
}

extern "C" void kernel_launch(void* const* d_in, const int* in_sizes, int n_in,
                              void* d_out, int out_size, void* d_ws, size_t ws_size,
                              hipStream_t stream) {
  const int*   tokens = (const int*)  d_in[0];
  const float* embed  = (const float*)d_in[1];
  const float* V      = (const float*)d_in[2];
  const float* W      = (const float*)d_in[3];
  const float* bias   = (const float*)d_in[4];
  const float* Wout   = (const float*)d_in[5];
  const float* bout   = (const float*)d_in[6];
  float* out = (float*)d_out;

  // ws: vhi 2MB | wt 16KB | bufA 4MB | bufB 2MB
  char* ws = (char*)d_ws;
  unsigned short* vhi = (unsigned short*)ws;
  unsigned short* wt  = (unsigned short*)(ws + 2097152);
  float* bufA = (float*)(ws + 2097152 + 16384);
  float* bufB = (float*)(ws + 2097152 + 16384 + 4194304);

  int nprep = kH * kH2 * kH2 + kH * kH2;
  prep_k<<<dim3((nprep + 255) / 256), 256, 0, stream>>>(V, W, vhi, wt);

  const float* cur = nullptr;
  float* nxt = bufA;
  bool first = true;
  for (int Nout = 256; Nout >= 1; Nout >>= 1) {
    int M  = kB * Nout;
    int gx = (M >= 128) ? (M / 128) : 1;
    int IS = gx / 8; if (IS < 1) IS = 1; if (IS > 16) IS = 16;
    dim3 grid(gx, 64 / IS);                     // L1: (128,4)=512 blocks, IS=16
    if (first)
      combine7_k<true ><<<grid, 256, 0, stream>>>(nullptr, tokens, embed, vhi, wt, bias, nxt, M, IS);
    else
      combine7_k<false><<<grid, 256, 0, stream>>>(cur, nullptr, nullptr, vhi, wt, bias, nxt, M, IS);
    first = false;
    cur = nxt;
    nxt = (nxt == bufA) ? bufB : bufA;
  }
  head_k<<<1, 64, 0, stream>>>(cur, Wout, bout, out);   // cur == bufA after 9 levels
}